// Round 7
// baseline (2486.152 us; speedup 1.0000x reference)
//
#include <hip/hip_runtime.h>
#include <math.h>

#define C_ 32
#define H_ 256
#define W_ 256
#define HW_ 65536
#define CHW_ 2097152          // one image's activation, floats
#define TWO_PI 6.28318530717958647692f

__device__ __forceinline__ float gelu_exact(float x) {
    return 0.5f * x * (1.0f + erff(x * 0.7071067811865475f));
}

// cos/sin(2*pi*t/256), t in [0,256). Phase reduced mod 256 (exact).
__device__ __forceinline__ void cs_tab(int t, float& c, float& s) {
    float a = TWO_PI * (1.0f / 256.0f) * (float)t;
    sincosf(a, &s, &c);
}

// ---------------------------------------------------------------------------
// PROBE fallback: encode ws_size (KiB) into d_out[0] so the harness's error
// printout measures it. Only used if ws can't hold even the per-image plan.
// ---------------------------------------------------------------------------
__global__ void k_probe(float* __restrict__ out, float ws_kib) {
    if (threadIdx.x == 0 && blockIdx.x == 0) out[0] = ws_kib;
}

// ---------------------------------------------------------------------------
// K1: lift. out[b,c,h,w] = sum_t in12[t]*fc0_w[t,c] + fc0_b[c]
// in12 = [x(10), gridx=h/255, gridy=w/255]. Thread = pixel; p encodes
// (b,h,w); batched: grid 2048; per-image: grid 256 with xb/out rebased (b=0).
// BUG FIX (the round-0..6 defect): fc0_w has 384 floats but blockDim is 256;
// the old `if (tid < 384)` left wsh[256..383] (features 8..11 = x8,x9,
// gridx,gridy) as uninitialized LDS garbage. Now a strided loop.
// ---------------------------------------------------------------------------
__global__ __launch_bounds__(256)
void k_lift(const float* __restrict__ xb, const float* __restrict__ fc0_w,
            const float* __restrict__ fc0_b, float* __restrict__ out) {
    __shared__ float wsh[12 * 32];
    __shared__ float bsh[32];
    int tid = threadIdx.x;
    for (int n = tid; n < 384; n += 256) wsh[n] = fc0_w[n];   // FIXED
    if (tid < 32) bsh[tid] = fc0_b[tid];
    __syncthreads();
    int p = blockIdx.x * 256 + tid;          // b<<16 | h<<8 | w
    int w = p & 255;
    int h = (p >> 8) & 255;
    float in[12];
    const float* xp = xb + (size_t)p * 10;
    #pragma unroll
    for (int t = 0; t < 10; ++t) in[t] = xp[t];
    in[10] = (float)h * (1.0f / 255.0f);     // gridx varies along H
    in[11] = (float)w * (1.0f / 255.0f);     // gridy varies along W
    float* op = out + (p & 0xFFFF) + (size_t)(p >> 16) * CHW_;
    #pragma unroll
    for (int c = 0; c < 32; ++c) {
        float acc = bsh[c];
        #pragma unroll
        for (int t = 0; t < 12; ++t) acc += in[t] * wsh[t * 32 + c];
        op[(size_t)c * HW_] = acc;
    }
}

// ---------------------------------------------------------------------------
// K2: forward W-DFT. S[row,kx] = sum_w X[row,w] e^{-2pi i kx w/256}
// row = (b*32+c)*256+h. Batched: grid 4096; per-image: grid 512, X rebased.
// ---------------------------------------------------------------------------
__global__ __launch_bounds__(256)
void k_dftw(const float* __restrict__ X, float* __restrict__ S) {
    int t = blockIdx.x * 256 + threadIdx.x;  // row*16 + kx
    int kx  = t & 15;
    int row = t >> 4;
    const float* xp = X + (size_t)row * 256;
    float re = 0.f, im = 0.f;
    for (int w = 0; w < 256; ++w) {
        float c, s; cs_tab((kx * w) & 255, c, s);
        float v = xp[w];
        re += v * c;                          // e^{-i θ}: (c, -s)
        im -= v * s;
    }
    ((float2*)S)[t] = make_float2(re, im);
}

// ---------------------------------------------------------------------------
// K3: forward H-DFT on kept rows.
// G[img,kyi,kx] = sum_h S[img,h,kx] e^{-2pi i ky h/256}, ky = kyi<16?kyi:224+kyi
// img = b*32+c. Batched: grid 512; per-image: grid 64, S/G rebased.
// ---------------------------------------------------------------------------
__global__ __launch_bounds__(256)
void k_dfth(const float* __restrict__ S, float* __restrict__ G) {
    int t = blockIdx.x * 256 + threadIdx.x;  // img*512 + kyi*16 + kx
    int kx  = t & 15;
    int kyi = (t >> 4) & 31;
    int img = t >> 9;
    int ky = kyi < 16 ? kyi : (224 + kyi);
    const float2* sp = (const float2*)S + (size_t)img * 4096 + kx;
    float gr = 0.f, gi = 0.f;
    for (int h = 0; h < 256; ++h) {
        float cc, ss; cs_tab((ky * h) & 255, cc, ss);
        float2 v = sp[(size_t)h * 16];
        gr += v.x * cc + v.y * ss;            // (x+iy)(c-is)
        gi += v.y * cc - v.x * ss;
    }
    ((float2*)G)[t] = make_float2(gr, gi);
}

// ---------------------------------------------------------------------------
// K4: per-(ky,kx) 32x32 complex channel mix.
// G2[b,o,kyi,kx] = sum_i G[b,i,kyi,kx] * W[i,o,kyj,kx]  (w1 kyi<16, else w2)
// Batched: grid 512 (b = t>>14); per-image: grid 64 (b=0), G/G2 rebased.
// ---------------------------------------------------------------------------
__global__ __launch_bounds__(256)
void k_mix(const float* __restrict__ G, const float* __restrict__ w1,
           const float* __restrict__ w2, float* __restrict__ G2) {
    int t = blockIdx.x * 256 + threadIdx.x;  // ((b*32+o)*32+kyi)*16+kx
    int kx  = t & 15;
    int kyi = (t >> 4) & 31;
    int o   = (t >> 9) & 31;
    int b   = t >> 14;
    const float* wp = (kyi < 16) ? w1 : w2;
    int kyj = kyi & 15;
    const float2* gp = (const float2*)G + (size_t)b * 16384 + (size_t)kyi * 16 + kx;
    float ar = 0.f, ai = 0.f;
    for (int i = 0; i < 32; ++i) {
        float2 g = gp[(size_t)i * 512];
        const float* wv = wp + ((((size_t)(i * 32 + o)) * 16 + kyj) * 16 + kx) * 2;
        ar += g.x * wv[0] - g.y * wv[1];
        ai += g.x * wv[1] + g.y * wv[0];
    }
    ((float2*)G2)[t] = make_float2(ar, ai);
}

// ---------------------------------------------------------------------------
// K5: inverse H-DFT; 1/(H*W) and hermitian x2 folded in.
// T[img,h,kx] = sc_kx * sum_kyi G2[img,kyi,kx] e^{+2pi i ky h/256}
// Batched: grid 4096; per-image: grid 512, G2/T rebased.
// ---------------------------------------------------------------------------
__global__ __launch_bounds__(256)
void k_idfth(const float* __restrict__ G2, float* __restrict__ T) {
    int t = blockIdx.x * 256 + threadIdx.x;  // (img*256+h)*16+kx
    int kx  = t & 15;
    int h   = (t >> 4) & 255;
    int img = t >> 12;
    const float2* gp = (const float2*)G2 + (size_t)img * 512 + kx;
    float tr = 0.f, ti = 0.f;
    for (int kyi = 0; kyi < 32; ++kyi) {
        int ky = kyi < 16 ? kyi : (224 + kyi);
        float cc, ss; cs_tab((ky * h) & 255, cc, ss);
        float2 v = gp[(size_t)kyi * 16];
        tr += v.x * cc - v.y * ss;            // (x+iy)(c+is)
        ti += v.x * ss + v.y * cc;
    }
    float sc = (kx == 0 ? 1.0f : 2.0f) * (1.0f / 65536.0f);
    ((float2*)T)[t] = make_float2(tr * sc, ti * sc);
}

// ---------------------------------------------------------------------------
// K6: inverse W-DFT + 1x1 conv + bias + GeLU + post-GeLU skip.
// X and Y may alias (in-place, batched path): each thread reads all 32 input
// channels of its own pixel into registers before any store; no cross-pixel
// access -> no __restrict__ on X/Y. Batched: grid 2048; per-image: grid 256.
// ---------------------------------------------------------------------------
__global__ __launch_bounds__(256)
void k_invw_conv(const float* __restrict__ T, const float* X,
                 const float* __restrict__ cw, const float* __restrict__ cb,
                 const float* __restrict__ skip, float* Y) {
    int b  = blockIdx.x >> 8;
    int hh = blockIdx.x & 255;
    int w  = threadIdx.x;
    float cA[16], sA[16];
    #pragma unroll
    for (int kx = 0; kx < 16; ++kx) {
        float c, s; cs_tab((kx * w) & 255, c, s);
        cA[kx] = c; sA[kx] = s;
    }
    size_t p = (size_t)b * CHW_ + (size_t)hh * W_ + w;
    float xv[32];
    const float* xp = X + p;
    #pragma unroll
    for (int i = 0; i < 32; ++i) xv[i] = xp[(size_t)i * HW_];
    const float* sp = skip ? skip + p : nullptr;
    float* yp = Y + p;
    for (int o = 0; o < 32; ++o) {
        const float2* tp = (const float2*)T + (((size_t)(b * 32 + o)) * 256 + hh) * 16;
        float acc = cb[o];
        #pragma unroll
        for (int kx = 0; kx < 16; ++kx) {
            float2 tv = tp[kx];
            acc += tv.x * cA[kx] - tv.y * sA[kx];   // Re((tr+i ti) e^{+iθ})
        }
        const float* cwp = cw + o * 32;
        #pragma unroll
        for (int i = 0; i < 32; ++i) acc += xv[i] * cwp[i];
        float g = gelu_exact(acc);
        if (sp) g += sp[(size_t)o * HW_];
        yp[(size_t)o * HW_] = g;
    }
}

// ---------------------------------------------------------------------------
// K7: MLP head. out[b,h,w,:] = gelu(h@fc1_w+fc1_b)@fc2_w + fc2_b
// Batched: grid 2048; per-image: grid 256, X/outb rebased (b=0).
// ---------------------------------------------------------------------------
__global__ __launch_bounds__(256)
void k_mlp(const float* __restrict__ X, const float* __restrict__ fc1_w,
           const float* __restrict__ fc1_b, const float* __restrict__ fc2_w,
           const float* __restrict__ fc2_b, float* __restrict__ outb) {
    __shared__ float w1sh[32 * 128];
    __shared__ float b1sh[128];
    __shared__ float w2sh[128 * 5];
    __shared__ float b2sh[5];
    int tid = threadIdx.x;
    for (int n = tid; n < 4096; n += 256) w1sh[n] = fc1_w[n];
    for (int n = tid; n < 640; n += 256)  w2sh[n] = fc2_w[n];
    if (tid < 128) b1sh[tid] = fc1_b[tid];
    if (tid < 5)   b2sh[tid] = fc2_b[tid];
    __syncthreads();
    int b  = blockIdx.x >> 8;
    int hh = blockIdx.x & 255;
    int w  = tid;
    float xv[32];
    const float* xp = X + (size_t)b * CHW_ + (size_t)hh * W_ + w;
    #pragma unroll
    for (int i = 0; i < 32; ++i) xv[i] = xp[(size_t)i * HW_];
    float o5[5] = {0.f, 0.f, 0.f, 0.f, 0.f};
    for (int d = 0; d < 128; ++d) {
        float a = b1sh[d];
        #pragma unroll
        for (int i = 0; i < 32; ++i) a += xv[i] * w1sh[i * 128 + d];
        float g = gelu_exact(a);
        #pragma unroll
        for (int s = 0; s < 5; ++s) o5[s] += g * w2sh[d * 5 + s];
    }
    float* op = outb + ((size_t)blockIdx.x * 256 + w) * 5;
    #pragma unroll
    for (int s = 0; s < 5; ++s) op[s] = o5[s] + b2sh[s];
}

// ---------------------------------------------------------------------------
extern "C" void kernel_launch(void* const* d_in, const int* in_sizes, int n_in,
                              void* d_out, int out_size, void* d_ws, size_t ws_size,
                              hipStream_t stream) {
    const float* x      = (const float*)d_in[0];
    const float* fc0_w  = (const float*)d_in[1];
    const float* fc0_b  = (const float*)d_in[2];
    const float* w1     = (const float*)d_in[3];
    const float* w2     = (const float*)d_in[4];
    const float* conv_w = (const float*)d_in[5];
    const float* conv_b = (const float*)d_in[6];
    const float* fc1_w  = (const float*)d_in[7];
    const float* fc1_b  = (const float*)d_in[8];
    const float* fc2_w  = (const float*)d_in[9];
    const float* fc2_b  = (const float*)d_in[10];
    float* out = (float*)d_out;

    const size_t ACTb = 16777216;            // batched activation, floats
    const size_t ACTi = 2097152;             // per-image activation, floats
    const size_t STb = 2097152, Gb = 262144; // batched spectral, floats
    const size_t STi = 262144,  Gi = 32768;  // per-image spectral, floats

    if (ws_size >= 2 * ACTb * sizeof(float)) {
        // ---- BATCHED PATH: 37 launches. A0,A1 in ws (128 MiB); ST+G+G2
        // pack exactly into d_out (2097152+262144+262144 = 2621440 floats =
        // out_size); dead before k_mlp rewrites every element of d_out.
        float* A0 = (float*)d_ws;
        float* A1 = A0 + ACTb;
        float* ST = out;
        float* G  = ST + STb;
        float* G2 = G + Gb;

        k_lift<<<2048, 256, 0, stream>>>(x, fc0_w, fc0_b, A0);
        auto layer = [&](int l, const float* Xin, float* Yout, const float* skip) {
            k_dftw<<<4096, 256, 0, stream>>>(Xin, ST);
            k_dfth<<<512, 256, 0, stream>>>(ST, G);
            k_mix<<<512, 256, 0, stream>>>(G, w1 + (size_t)l * 524288,
                                           w2 + (size_t)l * 524288, G2);
            k_idfth<<<4096, 256, 0, stream>>>(G2, ST);
            k_invw_conv<<<2048, 256, 0, stream>>>(ST, Xin, conv_w + (size_t)l * 1024,
                                                  conv_b + (size_t)l * 32, skip, Yout);
        };
        // h0=f(h,0); h=f(h,1); h=f(h,2)+h0; h1=f(h,3); h=f(h,4); h=f(h,5)+h1
        layer(0, A0, A1, nullptr);   // A1 = h0
        layer(1, A0, A0, nullptr);   // in-place (per-pixel safe)
        layer(2, A0, A0, A1);        // in-place, +h0
        layer(3, A0, A1, nullptr);   // A1 = h1 (h0 dead)
        layer(4, A0, A0, nullptr);   // in-place
        layer(5, A0, A0, A1);        // in-place, +h1
        k_mlp<<<2048, 256, 0, stream>>>(A0, fc1_w, fc1_b, fc2_w, fc2_b, out);

    } else if (ws_size >= (3 * ACTi + STi + 2 * Gi) * sizeof(float)) {
        // ---- PER-IMAGE PATH (round-6 structure, proven to fit): 26.3 MB.
        float* A0 = (float*)d_ws;
        float* A1 = A0 + ACTi;
        float* A2 = A1 + ACTi;
        float* ST = A2 + ACTi;
        float* G  = ST + STi;
        float* G2 = G + Gi;

        auto layer = [&](int l, const float* Xin, float* Yout, const float* skip) {
            k_dftw<<<512, 256, 0, stream>>>(Xin, ST);
            k_dfth<<<64, 256, 0, stream>>>(ST, G);
            k_mix<<<64, 256, 0, stream>>>(G, w1 + (size_t)l * 524288,
                                          w2 + (size_t)l * 524288, G2);
            k_idfth<<<512, 256, 0, stream>>>(G2, ST);
            k_invw_conv<<<256, 256, 0, stream>>>(ST, Xin, conv_w + (size_t)l * 1024,
                                                 conv_b + (size_t)l * 32, skip, Yout);
        };
        for (int b = 0; b < 8; ++b) {
            k_lift<<<256, 256, 0, stream>>>(x + (size_t)b * HW_ * 10, fc0_w, fc0_b, A0);
            layer(0, A0, A2, nullptr);   // A2 = h0
            layer(1, A0, A1, nullptr);
            layer(2, A1, A0, A2);        // +h0
            layer(3, A0, A2, nullptr);   // A2 = h1
            layer(4, A0, A1, nullptr);
            layer(5, A1, A0, A2);        // +h1
            k_mlp<<<256, 256, 0, stream>>>(A0, fc1_w, fc1_b, fc2_w, fc2_b,
                                           out + (size_t)b * 327680);
        }
    } else {
        k_probe<<<1, 64, 0, stream>>>(out, (float)(ws_size >> 10));
    }
}

// Round 9
// 1152.946 us; speedup vs baseline: 2.1563x; 2.1563x over previous
//
// Round 9 = round 8 resubmitted verbatim: round 8's bench was an
// infrastructure failure ("MI355X container failed twice"), not a verdict.
#include <hip/hip_runtime.h>
#include <math.h>

#define C_ 32
#define H_ 256
#define W_ 256
#define HW_ 65536
#define CHW_ 2097152          // one image's activation, floats
#define TWO_PI 6.28318530717958647692f

__device__ __forceinline__ float gelu_exact(float x) {
    return 0.5f * x * (1.0f + erff(x * 0.7071067811865475f));
}

// Build the 256-entry twiddle table tw[t] = (cos, sin)(2*pi*t/256) in LDS.
// One sincosf per thread, once per block — same values as the verified
// round-7 kernels (phases are mod-256-reduced there too).
__device__ __forceinline__ void build_tw(float2* tw, int tid) {
    float a = TWO_PI * (1.0f / 256.0f) * (float)tid;
    float s_, c_; sincosf(a, &s_, &c_);
    tw[tid] = make_float2(c_, s_);
}

// ---------------------------------------------------------------------------
// PROBE fallback (kept from r6): encode ws_size KiB in d_out[0].
// ---------------------------------------------------------------------------
__global__ void k_probe(float* __restrict__ out, float ws_kib) {
    if (threadIdx.x == 0 && blockIdx.x == 0) out[0] = ws_kib;
}

// ---------------------------------------------------------------------------
// K1: lift. out[b,c,h,w] = sum_t in12[t]*fc0_w[t,c] + fc0_b[c]
// (r7 bug fix retained: strided 384-element weight load.)
// ---------------------------------------------------------------------------
__global__ __launch_bounds__(256)
void k_lift(const float* __restrict__ xb, const float* __restrict__ fc0_w,
            const float* __restrict__ fc0_b, float* __restrict__ out) {
    __shared__ float wsh[12 * 32];
    __shared__ float bsh[32];
    int tid = threadIdx.x;
    for (int n = tid; n < 384; n += 256) wsh[n] = fc0_w[n];
    if (tid < 32) bsh[tid] = fc0_b[tid];
    __syncthreads();
    int p = blockIdx.x * 256 + tid;          // b<<16 | h<<8 | w
    int w = p & 255;
    int h = (p >> 8) & 255;
    float in[12];
    const float* xp = xb + (size_t)p * 10;
    #pragma unroll
    for (int t = 0; t < 10; ++t) in[t] = xp[t];
    in[10] = (float)h * (1.0f / 255.0f);
    in[11] = (float)w * (1.0f / 255.0f);
    float* op = out + (p & 0xFFFF) + (size_t)(p >> 16) * CHW_;
    #pragma unroll
    for (int c = 0; c < 32; ++c) {
        float acc = bsh[c];
        #pragma unroll
        for (int t = 0; t < 12; ++t) acc += in[t] * wsh[t * 32 + c];
        op[(size_t)c * HW_] = acc;
    }
}

// ---------------------------------------------------------------------------
// K2: forward W-DFT, twiddle-table + LDS row staging.
// S[row,kx] = sum_w X[row,w] e^{-i 2pi kx w/256}. 16 rows/block; thread=(r,kx).
// Batched grid 4096; per-image grid 512. Inner loop: 1 broadcast row read +
// 1 ds_read_b64 twiddle + 2 FMA; t advances incrementally (t += kx mod 256).
// ---------------------------------------------------------------------------
__global__ __launch_bounds__(256)
void k_dftw(const float* __restrict__ X, float* __restrict__ S) {
    __shared__ float2 tw[256];
    __shared__ float rows[16][257];          // +1 pad: r-groups conflict-free
    int tid = threadIdx.x;
    build_tw(tw, tid);
    const float* xp = X + (size_t)blockIdx.x * 4096;
    #pragma unroll
    for (int i = 0; i < 16; ++i) rows[i][tid] = xp[i * 256 + tid];
    __syncthreads();
    int r = tid >> 4, kx = tid & 15;
    const float* rp = rows[r];
    float re = 0.f, im = 0.f;
    int t = 0;
    #pragma unroll 8
    for (int w = 0; w < 256; ++w) {
        float v = rp[w];
        float2 cs = tw[t];
        re += v * cs.x;                       // e^{-i θ}: (c, -s)
        im -= v * cs.y;
        t = (t + kx) & 255;
    }
    ((float2*)S)[(size_t)blockIdx.x * 256 + tid] = make_float2(re, im);
}

// ---------------------------------------------------------------------------
// K3: forward H-DFT, block per img. G[img,kyi,kx] = sum_h S[img,h,kx] e^{-iθ},
// ky = kyi<16?kyi:224+kyi. S-slice staged in LDS (32 KB). 2 outputs/thread.
// Batched grid 256; per-image grid 32.
// ---------------------------------------------------------------------------
__global__ __launch_bounds__(256)
void k_dfth(const float* __restrict__ S, float* __restrict__ G) {
    __shared__ float2 tw[256];
    __shared__ float2 sl[256][16];           // 32 KB
    int tid = threadIdx.x;
    build_tw(tw, tid);
    const float2* sp = (const float2*)S + (size_t)blockIdx.x * 4096;
    #pragma unroll
    for (int i = 0; i < 16; ++i) {
        int n = i * 256 + tid;
        sl[n >> 4][n & 15] = sp[n];
    }
    __syncthreads();
    for (int o = tid; o < 512; o += 256) {
        int kyi = o >> 4, kx = o & 15;
        int ky = kyi < 16 ? kyi : (224 + kyi);
        float gr = 0.f, gi = 0.f;
        int t = 0;
        #pragma unroll 8
        for (int h = 0; h < 256; ++h) {
            float2 cs = tw[t];
            float2 v = sl[h][kx];
            gr += v.x * cs.x + v.y * cs.y;    // (x+iy)(c-is)
            gi += v.y * cs.x - v.x * cs.y;
            t = (t + ky) & 255;
        }
        ((float2*)G)[(size_t)blockIdx.x * 512 + o] = make_float2(gr, gi);
    }
}

// ---------------------------------------------------------------------------
// K4: per-(ky,kx) 32x32 complex channel mix (unchanged: ~10 us total share).
// Batched grid 512 (b = t>>14); per-image grid 64.
// ---------------------------------------------------------------------------
__global__ __launch_bounds__(256)
void k_mix(const float* __restrict__ G, const float* __restrict__ w1,
           const float* __restrict__ w2, float* __restrict__ G2) {
    int t = blockIdx.x * 256 + threadIdx.x;  // ((b*32+o)*32+kyi)*16+kx
    int kx  = t & 15;
    int kyi = (t >> 4) & 31;
    int o   = (t >> 9) & 31;
    int b   = t >> 14;
    const float* wp = (kyi < 16) ? w1 : w2;
    int kyj = kyi & 15;
    const float2* gp = (const float2*)G + (size_t)b * 16384 + (size_t)kyi * 16 + kx;
    float ar = 0.f, ai = 0.f;
    for (int i = 0; i < 32; ++i) {
        float2 g = gp[(size_t)i * 512];
        const float* wv = wp + ((((size_t)(i * 32 + o)) * 16 + kyj) * 16 + kx) * 2;
        ar += g.x * wv[0] - g.y * wv[1];
        ai += g.x * wv[1] + g.y * wv[0];
    }
    ((float2*)G2)[t] = make_float2(ar, ai);
}

// ---------------------------------------------------------------------------
// K5: inverse H-DFT, block per img, thread = h; 1/(H*W) and hermitian x2
// folded in. G2-slice staged in LDS (4 KB); 16 kx accumulators in registers.
// Batched grid 256; per-image grid 32.
// ---------------------------------------------------------------------------
__global__ __launch_bounds__(256)
void k_idfth(const float* __restrict__ G2, float* __restrict__ T) {
    __shared__ float2 tw[256];
    __shared__ float2 g[32][16];             // 4 KB
    int tid = threadIdx.x;
    build_tw(tw, tid);
    const float2* gp = (const float2*)G2 + (size_t)blockIdx.x * 512;
    for (int n = tid; n < 512; n += 256) g[n >> 4][n & 15] = gp[n];
    __syncthreads();
    int h = tid;
    float2 acc[16];
    #pragma unroll
    for (int kx = 0; kx < 16; ++kx) acc[kx] = make_float2(0.f, 0.f);
    for (int kyi = 0; kyi < 32; ++kyi) {
        int ky = kyi < 16 ? kyi : (224 + kyi);
        float2 cs = tw[(ky * h) & 255];
        #pragma unroll
        for (int kx = 0; kx < 16; ++kx) {
            float2 v = g[kyi][kx];
            acc[kx].x += v.x * cs.x - v.y * cs.y;   // (x+iy)(c+is)
            acc[kx].y += v.x * cs.y + v.y * cs.x;
        }
    }
    float2* tp = (float2*)T + ((size_t)blockIdx.x * 256 + h) * 16;
    #pragma unroll
    for (int kx = 0; kx < 16; ++kx) {
        float sc = (kx == 0 ? 1.0f : 2.0f) * (1.0f / 65536.0f);
        tp[kx] = make_float2(acc[kx].x * sc, acc[kx].y * sc);
    }
}

// ---------------------------------------------------------------------------
// K6: inverse W-DFT + 1x1 conv + bias + GeLU + post-GeLU skip.
// T-slice, conv weights, bias staged in LDS; cA/sA from twiddle table.
// X and Y may alias (per-pixel read-before-write). Batched grid 2048;
// per-image grid 256 (b = blockIdx>>8 = 0).
// ---------------------------------------------------------------------------
__global__ __launch_bounds__(256)
void k_invw_conv(const float* __restrict__ T, const float* X,
                 const float* __restrict__ cw, const float* __restrict__ cb,
                 const float* __restrict__ skip, float* Y) {
    __shared__ float2 tw[256];
    __shared__ float2 tsh[32][16];           // 4 KB
    __shared__ float cwsh[32][32];           // 4 KB
    __shared__ float cbsh[32];
    int tid = threadIdx.x;
    build_tw(tw, tid);
    int b  = blockIdx.x >> 8;
    int hh = blockIdx.x & 255;
    const float2* tp = (const float2*)T;
    for (int n = tid; n < 512; n += 256) {
        int o = n >> 4, kx = n & 15;
        tsh[o][kx] = tp[(((size_t)(b * 32 + o)) * 256 + hh) * 16 + kx];
    }
    for (int n = tid; n < 1024; n += 256) cwsh[n >> 5][n & 31] = cw[n];
    if (tid < 32) cbsh[tid] = cb[tid];
    __syncthreads();
    int w = tid;
    float cA[16], sA[16];
    #pragma unroll
    for (int kx = 0; kx < 16; ++kx) {
        float2 cs = tw[(kx * w) & 255];
        cA[kx] = cs.x; sA[kx] = cs.y;
    }
    size_t p = (size_t)b * CHW_ + (size_t)hh * W_ + w;
    float xv[32];
    const float* xp = X + p;
    #pragma unroll
    for (int i = 0; i < 32; ++i) xv[i] = xp[(size_t)i * HW_];
    const float* sp = skip ? skip + p : nullptr;
    float* yp = Y + p;
    for (int o = 0; o < 32; ++o) {
        float acc = cbsh[o];
        #pragma unroll
        for (int kx = 0; kx < 16; ++kx) {
            float2 tv = tsh[o][kx];
            acc += tv.x * cA[kx] - tv.y * sA[kx];   // Re((tr+i ti) e^{+iθ})
        }
        #pragma unroll
        for (int i = 0; i < 32; ++i) acc += xv[i] * cwsh[o][i];
        float g = gelu_exact(acc);
        if (sp) g += sp[(size_t)o * HW_];
        yp[(size_t)o * HW_] = g;
    }
}

// ---------------------------------------------------------------------------
// K7: MLP head (unchanged). Batched grid 2048; per-image grid 256.
// ---------------------------------------------------------------------------
__global__ __launch_bounds__(256)
void k_mlp(const float* __restrict__ X, const float* __restrict__ fc1_w,
           const float* __restrict__ fc1_b, const float* __restrict__ fc2_w,
           const float* __restrict__ fc2_b, float* __restrict__ outb) {
    __shared__ float w1sh[32 * 128];
    __shared__ float b1sh[128];
    __shared__ float w2sh[128 * 5];
    __shared__ float b2sh[5];
    int tid = threadIdx.x;
    for (int n = tid; n < 4096; n += 256) w1sh[n] = fc1_w[n];
    for (int n = tid; n < 640; n += 256)  w2sh[n] = fc2_w[n];
    if (tid < 128) b1sh[tid] = fc1_b[tid];
    if (tid < 5)   b2sh[tid] = fc2_b[tid];
    __syncthreads();
    int b  = blockIdx.x >> 8;
    int hh = blockIdx.x & 255;
    int w  = tid;
    float xv[32];
    const float* xp = X + (size_t)b * CHW_ + (size_t)hh * W_ + w;
    #pragma unroll
    for (int i = 0; i < 32; ++i) xv[i] = xp[(size_t)i * HW_];
    float o5[5] = {0.f, 0.f, 0.f, 0.f, 0.f};
    for (int d = 0; d < 128; ++d) {
        float a = b1sh[d];
        #pragma unroll
        for (int i = 0; i < 32; ++i) a += xv[i] * w1sh[i * 128 + d];
        float g = gelu_exact(a);
        #pragma unroll
        for (int s = 0; s < 5; ++s) o5[s] += g * w2sh[d * 5 + s];
    }
    float* op = outb + ((size_t)blockIdx.x * 256 + w) * 5;
    #pragma unroll
    for (int s = 0; s < 5; ++s) op[s] = o5[s] + b2sh[s];
}

// ---------------------------------------------------------------------------
extern "C" void kernel_launch(void* const* d_in, const int* in_sizes, int n_in,
                              void* d_out, int out_size, void* d_ws, size_t ws_size,
                              hipStream_t stream) {
    const float* x      = (const float*)d_in[0];
    const float* fc0_w  = (const float*)d_in[1];
    const float* fc0_b  = (const float*)d_in[2];
    const float* w1     = (const float*)d_in[3];
    const float* w2     = (const float*)d_in[4];
    const float* conv_w = (const float*)d_in[5];
    const float* conv_b = (const float*)d_in[6];
    const float* fc1_w  = (const float*)d_in[7];
    const float* fc1_b  = (const float*)d_in[8];
    const float* fc2_w  = (const float*)d_in[9];
    const float* fc2_b  = (const float*)d_in[10];
    float* out = (float*)d_out;

    const size_t ACTb = 16777216;            // batched activation, floats
    const size_t ACTi = 2097152;             // per-image activation, floats
    const size_t STb = 2097152, Gb = 262144; // batched spectral, floats
    const size_t STi = 262144,  Gi = 32768;  // per-image spectral, floats

    if (ws_size >= 2 * ACTb * sizeof(float)) {
        // ---- BATCHED PATH (confirmed live in r7: WRITE_SIZE 8 MB on k_dftw).
        // A0,A1 in ws (128 MiB); ST+G+G2 pack exactly into d_out (2621440
        // floats = out_size), dead before k_mlp rewrites all of d_out.
        float* A0 = (float*)d_ws;
        float* A1 = A0 + ACTb;
        float* ST = out;
        float* G  = ST + STb;
        float* G2 = G + Gb;

        k_lift<<<2048, 256, 0, stream>>>(x, fc0_w, fc0_b, A0);
        auto layer = [&](int l, const float* Xin, float* Yout, const float* skip) {
            k_dftw<<<4096, 256, 0, stream>>>(Xin, ST);
            k_dfth<<<256, 256, 0, stream>>>(ST, G);
            k_mix<<<512, 256, 0, stream>>>(G, w1 + (size_t)l * 524288,
                                           w2 + (size_t)l * 524288, G2);
            k_idfth<<<256, 256, 0, stream>>>(G2, ST);
            k_invw_conv<<<2048, 256, 0, stream>>>(ST, Xin, conv_w + (size_t)l * 1024,
                                                  conv_b + (size_t)l * 32, skip, Yout);
        };
        // h0=f(h,0); h=f(h,1); h=f(h,2)+h0; h1=f(h,3); h=f(h,4); h=f(h,5)+h1
        layer(0, A0, A1, nullptr);   // A1 = h0
        layer(1, A0, A0, nullptr);   // in-place (per-pixel safe)
        layer(2, A0, A0, A1);        // in-place, +h0
        layer(3, A0, A1, nullptr);   // A1 = h1 (h0 dead)
        layer(4, A0, A0, nullptr);   // in-place
        layer(5, A0, A0, A1);        // in-place, +h1
        k_mlp<<<2048, 256, 0, stream>>>(A0, fc1_w, fc1_b, fc2_w, fc2_b, out);

    } else if (ws_size >= (3 * ACTi + STi + 2 * Gi) * sizeof(float)) {
        // ---- PER-IMAGE PATH (fallback; same kernels, rebased pointers).
        float* A0 = (float*)d_ws;
        float* A1 = A0 + ACTi;
        float* A2 = A1 + ACTi;
        float* ST = A2 + ACTi;
        float* G  = ST + STi;
        float* G2 = G + Gi;

        auto layer = [&](int l, const float* Xin, float* Yout, const float* skip) {
            k_dftw<<<512, 256, 0, stream>>>(Xin, ST);
            k_dfth<<<32, 256, 0, stream>>>(ST, G);
            k_mix<<<64, 256, 0, stream>>>(G, w1 + (size_t)l * 524288,
                                          w2 + (size_t)l * 524288, G2);
            k_idfth<<<32, 256, 0, stream>>>(G2, ST);
            k_invw_conv<<<256, 256, 0, stream>>>(ST, Xin, conv_w + (size_t)l * 1024,
                                                 conv_b + (size_t)l * 32, skip, Yout);
        };
        for (int b = 0; b < 8; ++b) {
            k_lift<<<256, 256, 0, stream>>>(x + (size_t)b * HW_ * 10, fc0_w, fc0_b, A0);
            layer(0, A0, A2, nullptr);   // A2 = h0
            layer(1, A0, A1, nullptr);
            layer(2, A1, A0, A2);        // +h0
            layer(3, A0, A2, nullptr);   // A2 = h1
            layer(4, A0, A1, nullptr);
            layer(5, A1, A0, A2);        // +h1
            k_mlp<<<256, 256, 0, stream>>>(A0, fc1_w, fc1_b, fc2_w, fc2_b,
                                           out + (size_t)b * 327680);
        }
    } else {
        k_probe<<<1, 64, 0, stream>>>(out, (float)(ws_size >> 10));
    }
}